// Round 10
// baseline (284.414 us; speedup 1.0000x reference)
//
#include <hip/hip_runtime.h>
#include <hip/hip_bf16.h>

#define N_NODES 50000
#define N_EDGES 800000
#define D 128
#define LABEL_DIM 32
#define REL_DIM 32
#define REL_BUCKETS 1024
#define NUM_LABELS 1000
#define LN_EPS 1e-5f

#define NB 196     // dst buckets of 256 nodes
#define EPB 1024   // edges per bin_scatter block (4/thread)

typedef short bf16x8 __attribute__((ext_vector_type(8)));
typedef float f32x4 __attribute__((ext_vector_type(4)));

__device__ inline unsigned short f2bf(float f) {
    __hip_bfloat16 h = __float2bfloat16(f);
    return *reinterpret_cast<unsigned short*>(&h);
}
__device__ inline float bf2f(unsigned short u) {
    return __uint_as_float((unsigned)u << 16);
}
// dword holding 2 bf16 -> (lo, hi) as fp32: 1 VALU each (shl / and)
__device__ inline float2 bfpair(unsigned d) {
    return make_float2(__uint_as_float(d << 16), __uint_as_float(d & 0xffff0000u));
}
__device__ inline float2 add2(float2 a, float2 b) {
    return make_float2(a.x + b.x, a.y + b.y);
}

// ---------------- CSR build (bucketed, no global per-node atomics) ----------------

__global__ __launch_bounds__(256) void bucket_count_kernel(const int* __restrict__ dst,
                                                           int* __restrict__ gbh) {
    __shared__ int hsh[NB];
    const int t = threadIdx.x;
    for (int i = t; i < NB; i += 256) hsh[i] = 0;
    __syncthreads();
    for (int e = blockIdx.x * 256 + t; e < N_EDGES; e += gridDim.x * 256)
        atomicAdd(&hsh[dst[e] >> 8], 1);
    __syncthreads();
    for (int i = t; i < NB; i += 256)
        if (hsh[i]) atomicAdd(&gbh[i], hsh[i]);
}

__global__ __launch_bounds__(256) void bucket_scan_kernel(const int* __restrict__ gbh,
                                                          int* __restrict__ bucket_off,
                                                          int* __restrict__ gcur) {
    __shared__ int buf[256];
    const int t = threadIdx.x;
    int v = (t < NB) ? gbh[t] : 0;
    buf[t] = v;
    __syncthreads();
    for (int off = 1; off < 256; off <<= 1) {
        int tv = (t >= off) ? buf[t - off] : 0;
        __syncthreads();
        buf[t] += tv;
        __syncthreads();
    }
    int excl = buf[t] - v;
    if (t < NB) {
        bucket_off[t] = excl;
        gcur[t] = excl;
    }
    if (t == NB - 1) bucket_off[NB] = excl + v;
}

__global__ __launch_bounds__(256) void bin_scatter_kernel(const int* __restrict__ src,
                                                          const int* __restrict__ dst,
                                                          const int* __restrict__ rel,
                                                          int* __restrict__ gcur,
                                                          unsigned* __restrict__ staged_pk,
                                                          unsigned char* __restrict__ staged_dl) {
    __shared__ int hist[NB];
    __shared__ int lcur[NB];
    const int t = threadIdx.x;
    for (int i = t; i < NB; i += 256) hist[i] = 0;
    __syncthreads();
    const int e0 = blockIdx.x * EPB;
    unsigned char bb[4], dl[4];
#pragma unroll
    for (int i = 0; i < 4; ++i) {
        int e = e0 + i * 256 + t;
        if (e < N_EDGES) {
            int d = dst[e];
            bb[i] = (unsigned char)(d >> 8);
            dl[i] = (unsigned char)(d & 255);
            atomicAdd(&hist[d >> 8], 1);
        }
    }
    __syncthreads();
    for (int b = t; b < NB; b += 256) {
        int hc = hist[b];
        lcur[b] = hc ? atomicAdd(&gcur[b], hc) : 0;
    }
    __syncthreads();
#pragma unroll
    for (int i = 0; i < 4; ++i) {
        int e = e0 + i * 256 + t;
        if (e < N_EDGES) {
            int pos = atomicAdd(&lcur[bb[i]], 1);
            staged_pk[pos] = (unsigned)src[e] | ((unsigned)rel[e] << 16);
            staged_dl[pos] = dl[i];
        }
    }
}

__global__ __launch_bounds__(512) void bin_place2_kernel(const int* __restrict__ bucket_off,
                                                         const unsigned* __restrict__ staged_pk,
                                                         const unsigned char* __restrict__ staged_dl,
                                                         int* __restrict__ offsets,
                                                         unsigned* __restrict__ csr_pk) {
    __shared__ int hist[256];
    __shared__ int buf[512];
    __shared__ int cur[256];
    const int b = blockIdx.x;
    const int t = threadIdx.x;
    const int beg = bucket_off[b], end = bucket_off[b + 1];
    if (t < 256) hist[t] = 0;
    __syncthreads();
    for (int i = beg + t; i < end; i += 512) atomicAdd(&hist[staged_dl[i]], 1);
    __syncthreads();
    int v = (t < 256) ? hist[t] : 0;
    buf[t] = v;
    __syncthreads();
    for (int off = 1; off < 512; off <<= 1) {
        int tv = (t >= off) ? buf[t - off] : 0;
        __syncthreads();
        buf[t] += tv;
        __syncthreads();
    }
    if (t < 256) {
        int node_off = beg + buf[t] - v;
        int node = b * 256 + t;
        if (node < N_NODES) offsets[node] = node_off;
        if (b == NB - 1 && t == 0) offsets[N_NODES] = end;
        cur[t] = node_off;
    }
    __syncthreads();
    for (int i = beg + t; i < end; i += 512) {
        int pos = atomicAdd(&cur[staged_dl[i]], 1);
        csr_pk[pos] = staged_pk[i];
    }
}

// ---------------- fused weight/embedding prep (one dispatch) ----------------
#define PB_IN 80      // 128*160/256
#define PB_LEMB 125   // 32000/256
#define PB_DUAL 128   // 256*128/256
#define PB_RELW 512   // 1024*128/256

__global__ __launch_bounds__(256) void prep_all_kernel(
    const float* __restrict__ in_proj_w, const float* __restrict__ label_emb,
    const float* __restrict__ lin_neigh_w, const float* __restrict__ lin_self_w,
    const float* __restrict__ rel_emb, const float* __restrict__ lin_rel_w,
    unsigned short* __restrict__ Btx, unsigned short* __restrict__ leb,
    unsigned short* __restrict__ Bt0, unsigned short* __restrict__ Bt1,
    unsigned short* __restrict__ relW0, unsigned short* __restrict__ relW1) {
    int bb = blockIdx.x;
    const int t = threadIdx.x;
    if (bb < PB_IN) {
        int idx = bb * 256 + t;
        int n = idx / 160, k = idx % 160;
        Btx[idx] = f2bf(in_proj_w[k * 128 + n]);
        return;
    }
    bb -= PB_IN;
    if (bb < PB_LEMB) {
        int i = bb * 256 + t;
        if (i < NUM_LABELS * LABEL_DIM) leb[i] = f2bf(label_emb[i]);
        return;
    }
    bb -= PB_LEMB;
    if (bb < 2 * PB_DUAL) {
        int l = bb >= PB_DUAL;
        if (l) bb -= PB_DUAL;
        int idx = bb * 256 + t;
        int n = idx >> 7, k = idx & 127;
        const float* Wn = lin_neigh_w + (size_t)l * 128 * 128;
        const float* Ws = lin_self_w + (size_t)l * 128 * 128;
        float v = (n < 128) ? Wn[k * 128 + n] : Ws[k * 128 + (n - 128)];
        (l ? Bt1 : Bt0)[idx] = f2bf(v);
        return;
    }
    bb -= 2 * PB_DUAL;
    {
        int l = bb >= PB_RELW;
        if (l) bb -= PB_RELW;
        const float* re_base = rel_emb + (size_t)l * REL_BUCKETS * REL_DIM;
        const float* Wr = lin_rel_w + (size_t)l * REL_DIM * 128;
        unsigned short* out = l ? relW1 : relW0;
        __shared__ float sw[REL_DIM * 128];
        for (int i = t; i < REL_DIM * 128; i += 256) sw[i] = Wr[i];
        __syncthreads();
        int idx = bb * 256 + t;
        int r = idx >> 7, c = idx & 127;
        const float* re = re_base + (size_t)r * REL_DIM;
        float a = 0.f;
#pragma unroll
        for (int k = 0; k < REL_DIM; k++) a = fmaf(re[k], sw[k * 128 + c], a);
        out[idx] = f2bf(a);
    }
}

// ---------------- dual MFMA GEMM: both halves, one dispatch, A read once ------
// A-fragments held in regs across two 32 KiB B-tile phases (hW, then hsb+bias).
__global__ __launch_bounds__(256) void mfma_dual2_kernel(const unsigned short* __restrict__ A,
                                                         const unsigned short* __restrict__ Bt,
                                                         const float* __restrict__ bias,
                                                         unsigned short* __restrict__ outHW,
                                                         unsigned short* __restrict__ outHS) {
    __shared__ unsigned short sB[128 * 128];  // 32 KiB, reloaded per phase
    const int t = threadIdx.x;
    const int wave = t >> 6, lane = t & 63;
    const int m16 = lane & 15, q = lane >> 4;
    const int r0 = blockIdx.x * 64 + wave * 16;
    const int arow = r0 + m16;
    const bool avalid = arow < N_NODES;
    const unsigned short* ap = A + (size_t)(avalid ? arow : 0) * 128 + q * 8;

    bf16x8 afr[4];
#pragma unroll
    for (int ki = 0; ki < 4; ++ki) {
        afr[ki] = *(const bf16x8*)(ap + ki * 32);
        if (!avalid) afr[ki] = (bf16x8){0, 0, 0, 0, 0, 0, 0, 0};
    }

#pragma unroll
    for (int half = 0; half < 2; ++half) {
        if (half) __syncthreads();  // drain phase-0 LDS reads before overwrite
        const unsigned short* Bsrc = Bt + (size_t)half * 128 * 128;
#pragma unroll
        for (int i = 0; i < 8; ++i) {
            int c = t + i * 256;
            int col = c >> 4, kch = c & 15;
            int dstc = col * 16 + (kch ^ (col & 7));
            *(bf16x8*)&sB[dstc * 8] = *(const bf16x8*)&Bsrc[c * 8];
        }
        __syncthreads();

        f32x4 acc[8];
#pragma unroll
        for (int ct = 0; ct < 8; ++ct) acc[ct] = (f32x4){0.f, 0.f, 0.f, 0.f};
#pragma unroll
        for (int ki = 0; ki < 4; ++ki) {
            int kch = ki * 4 + q;
#pragma unroll
            for (int ct = 0; ct < 8; ++ct) {
                int col = ct * 16 + m16;
                int chunk = col * 16 + (kch ^ (m16 & 7));
                bf16x8 bf = *(const bf16x8*)&sB[chunk * 8];
                acc[ct] = __builtin_amdgcn_mfma_f32_16x16x32_bf16(afr[ki], bf, acc[ct], 0, 0, 0);
            }
        }

        if (half == 0) {
#pragma unroll
            for (int ct = 0; ct < 8; ++ct) {
                int colg = ct * 16 + m16;
#pragma unroll
                for (int r = 0; r < 4; ++r) {
                    int row = r0 + q * 4 + r;
                    if (row < N_NODES) outHW[(size_t)row * 128 + colg] = f2bf(acc[ct][r]);
                }
            }
        } else {
#pragma unroll
            for (int ct = 0; ct < 8; ++ct) {
                int colg = ct * 16 + m16;
                float bs = bias[colg];
#pragma unroll
                for (int r = 0; r < 4; ++r) {
                    int row = r0 + q * 4 + r;
                    if (row < N_NODES) outHS[(size_t)row * 128 + colg] = f2bf(acc[ct][r] + bs);
                }
            }
        }
    }
}

// ---------------- input-proj MFMA GEMM (fp32 A, K=160, fused lemb+bias+relu) ----
__global__ __launch_bounds__(256) void mfma_in_kernel(const float* __restrict__ X,
                                                      const unsigned short* __restrict__ Btx,
                                                      const unsigned short* __restrict__ leb,
                                                      const int* __restrict__ label,
                                                      const float* __restrict__ bias,
                                                      unsigned short* __restrict__ outBF) {
    __shared__ unsigned short sB[128 * 160];  // 40 KiB
    const int t = threadIdx.x;
#pragma unroll
    for (int i = 0; i < 10; ++i) {
        int c = t + i * 256;
        int col = c / 20, kch = c % 20;
        int dstc = col * 20 + (kch < 16 ? (kch ^ (col & 7)) : kch);
        *(bf16x8*)&sB[dstc * 8] = *(const bf16x8*)&Btx[c * 8];
    }
    __syncthreads();

    const int wave = t >> 6, lane = t & 63;
    const int m16 = lane & 15, q = lane >> 4;
    const int r0 = blockIdx.x * 64 + wave * 16;
    const int arow = r0 + m16;
    const bool avalid = arow < N_NODES;
    const float* xp = X + (size_t)(avalid ? arow : 0) * 128 + q * 8;

    f32x4 acc[8];
#pragma unroll
    for (int ct = 0; ct < 8; ++ct) acc[ct] = (f32x4){0.f, 0.f, 0.f, 0.f};

#pragma unroll
    for (int ki = 0; ki < 4; ++ki) {
        bf16x8 af;
        if (avalid) {
            float4 v0 = *(const float4*)(xp + ki * 32);
            float4 v1 = *(const float4*)(xp + ki * 32 + 4);
            af[0] = (short)f2bf(v0.x); af[1] = (short)f2bf(v0.y);
            af[2] = (short)f2bf(v0.z); af[3] = (short)f2bf(v0.w);
            af[4] = (short)f2bf(v1.x); af[5] = (short)f2bf(v1.y);
            af[6] = (short)f2bf(v1.z); af[7] = (short)f2bf(v1.w);
        } else {
            af = (bf16x8){0, 0, 0, 0, 0, 0, 0, 0};
        }
        int kch = ki * 4 + q;
#pragma unroll
        for (int ct = 0; ct < 8; ++ct) {
            int col = ct * 16 + m16;
            int chunk = col * 20 + (kch ^ (m16 & 7));
            bf16x8 bf = *(const bf16x8*)&sB[chunk * 8];
            acc[ct] = __builtin_amdgcn_mfma_f32_16x16x32_bf16(af, bf, acc[ct], 0, 0, 0);
        }
    }
    {
        int lb = avalid ? label[arow] : 0;
        bf16x8 af = *(const bf16x8*)(leb + (size_t)lb * LABEL_DIM + q * 8);
        if (!avalid) af = (bf16x8){0, 0, 0, 0, 0, 0, 0, 0};
        int kch = 16 + q;
#pragma unroll
        for (int ct = 0; ct < 8; ++ct) {
            int col = ct * 16 + m16;
            int chunk = col * 20 + kch;
            bf16x8 bf = *(const bf16x8*)&sB[chunk * 8];
            acc[ct] = __builtin_amdgcn_mfma_f32_16x16x32_bf16(af, bf, acc[ct], 0, 0, 0);
        }
    }

#pragma unroll
    for (int ct = 0; ct < 8; ++ct) {
        int colg = ct * 16 + m16;
        float bs = bias[colg];
#pragma unroll
        for (int r = 0; r < 4; ++r) {
            int row = r0 + q * 4 + r;
            if (row < N_NODES) {
                float v = fmaxf(acc[ct][r] + bs, 0.f);
                outBF[(size_t)row * 128 + colg] = f2bf(v);
            }
        }
    }
}

// ---------------- edge gather + mean + self + relu + layernorm ----------------
// One wave per node; quarter q handles edges e+q, e+4+q. Main loop = full
// 8-edge groups (no masks); masked tail. bf16 pairs unpacked as float2 and
// accumulated with float2 adds (v_pk_add_f32). Per-lane FP order identical to
// the masked version.
template <bool WF32, bool WBF16>
__global__ __launch_bounds__(256) void agg_ln_kernel(const unsigned short* __restrict__ hW,
                                                     const unsigned short* __restrict__ relW,
                                                     const unsigned short* __restrict__ hsb,
                                                     const int* __restrict__ offsets,
                                                     const unsigned* __restrict__ csr_pk,
                                                     const float* __restrict__ g,
                                                     const float* __restrict__ b,
                                                     float* __restrict__ h,
                                                     unsigned short* __restrict__ hb) {
    const int wave = threadIdx.x >> 6;
    const int lane = threadIdx.x & 63;
    const int node = blockIdx.x * 4 + wave;
    if (node >= N_NODES) return;
    const int q = lane >> 4, l16 = lane & 15;
    const int beg = offsets[node], end = offsets[node + 1];
    const int co = l16 * 8;

    float2 acc2[4];
#pragma unroll
    for (int j = 0; j < 4; ++j) acc2[j] = make_float2(0.f, 0.f);

    int e = beg;
    for (; e + 8 <= end; e += 8) {
        unsigned pk0 = csr_pk[e + q];
        unsigned pk1 = csr_pk[e + 4 + q];
        uint4 hv0 = *(const uint4*)(hW + ((size_t)(pk0 & 0xffffu) << 7) + co);
        uint4 rv0 = *(const uint4*)(relW + ((size_t)(pk0 >> 16) << 7) + co);
        uint4 hv1 = *(const uint4*)(hW + ((size_t)(pk1 & 0xffffu) << 7) + co);
        uint4 rv1 = *(const uint4*)(relW + ((size_t)(pk1 >> 16) << 7) + co);
        acc2[0] = add2(acc2[0], add2(bfpair(hv0.x), bfpair(rv0.x)));
        acc2[1] = add2(acc2[1], add2(bfpair(hv0.y), bfpair(rv0.y)));
        acc2[2] = add2(acc2[2], add2(bfpair(hv0.z), bfpair(rv0.z)));
        acc2[3] = add2(acc2[3], add2(bfpair(hv0.w), bfpair(rv0.w)));
        acc2[0] = add2(acc2[0], add2(bfpair(hv1.x), bfpair(rv1.x)));
        acc2[1] = add2(acc2[1], add2(bfpair(hv1.y), bfpair(rv1.y)));
        acc2[2] = add2(acc2[2], add2(bfpair(hv1.z), bfpair(rv1.z)));
        acc2[3] = add2(acc2[3], add2(bfpair(hv1.w), bfpair(rv1.w)));
    }
    if (e < end) {  // masked tail (1..7 edges)
        int i0 = e + q, i1 = e + 4 + q;
        float m0 = 1.f, m1 = 1.f;
        if (i0 >= end) { i0 = beg; m0 = 0.f; }
        if (i1 >= end) { i1 = beg; m1 = 0.f; }
        unsigned pk0 = csr_pk[i0];
        unsigned pk1 = csr_pk[i1];
        uint4 hv0 = *(const uint4*)(hW + ((size_t)(pk0 & 0xffffu) << 7) + co);
        uint4 rv0 = *(const uint4*)(relW + ((size_t)(pk0 >> 16) << 7) + co);
        uint4 hv1 = *(const uint4*)(hW + ((size_t)(pk1 & 0xffffu) << 7) + co);
        uint4 rv1 = *(const uint4*)(relW + ((size_t)(pk1 >> 16) << 7) + co);
        unsigned dw0[4] = {hv0.x, hv0.y, hv0.z, hv0.w};
        unsigned dr0[4] = {rv0.x, rv0.y, rv0.z, rv0.w};
        unsigned dw1[4] = {hv1.x, hv1.y, hv1.z, hv1.w};
        unsigned dr1[4] = {rv1.x, rv1.y, rv1.z, rv1.w};
#pragma unroll
        for (int j = 0; j < 4; ++j) {
            float2 v0 = add2(bfpair(dw0[j]), bfpair(dr0[j]));
            acc2[j].x = fmaf(m0, v0.x, acc2[j].x);
            acc2[j].y = fmaf(m0, v0.y, acc2[j].y);
        }
#pragma unroll
        for (int j = 0; j < 4; ++j) {
            float2 v1 = add2(bfpair(dw1[j]), bfpair(dr1[j]));
            acc2[j].x = fmaf(m1, v1.x, acc2[j].x);
            acc2[j].y = fmaf(m1, v1.y, acc2[j].y);
        }
    }

    // acc layout: acc2[j] = cols (co + 2j, co + 2j + 1)
    float acc[8];
#pragma unroll
    for (int j = 0; j < 4; ++j) {
        acc[2 * j] = acc2[j].x;
        acc[2 * j + 1] = acc2[j].y;
    }
#pragma unroll
    for (int j = 0; j < 8; ++j) {
        acc[j] += __shfl_xor(acc[j], 16);
        acc[j] += __shfl_xor(acc[j], 32);
    }

    float inv = (end > beg) ? 1.f / (float)(end - beg) : 0.f;
    bf16x8 hsv = *(const bf16x8*)(hsb + ((size_t)node << 7) + co);
    float v[8];
    float s_sum = 0.f;
#pragma unroll
    for (int j = 0; j < 8; ++j) {
        v[j] = fmaxf(bf2f((unsigned short)hsv[j]) + acc[j] * inv, 0.f);
        s_sum += v[j];
    }
#pragma unroll
    for (int o = 8; o > 0; o >>= 1) s_sum += __shfl_xor(s_sum, o);
    float mu = s_sum * (1.f / 128.f);
    float qs = 0.f;
    float d[8];
#pragma unroll
    for (int j = 0; j < 8; ++j) {
        d[j] = v[j] - mu;
        qs += d[j] * d[j];
    }
#pragma unroll
    for (int o = 8; o > 0; o >>= 1) qs += __shfl_xor(qs, o);
    float rstd = rsqrtf(qs * (1.f / 128.f) + LN_EPS);

    if (q == 0) {
        float4 g0 = *(const float4*)(g + co), g1 = *(const float4*)(g + co + 4);
        float4 b0 = *(const float4*)(b + co), b1 = *(const float4*)(b + co + 4);
        float o0 = d[0] * rstd * g0.x + b0.x;
        float o1 = d[1] * rstd * g0.y + b0.y;
        float o2 = d[2] * rstd * g0.z + b0.z;
        float o3 = d[3] * rstd * g0.w + b0.w;
        float o4 = d[4] * rstd * g1.x + b1.x;
        float o5 = d[5] * rstd * g1.y + b1.y;
        float o6 = d[6] * rstd * g1.z + b1.z;
        float o7 = d[7] * rstd * g1.w + b1.w;
        if (WF32) {
            *(float4*)(h + ((size_t)node << 7) + co) = make_float4(o0, o1, o2, o3);
            *(float4*)(h + ((size_t)node << 7) + co + 4) = make_float4(o4, o5, o6, o7);
        }
        if (WBF16) {
            bf16x8 ob;
            ob[0] = (short)f2bf(o0); ob[1] = (short)f2bf(o1);
            ob[2] = (short)f2bf(o2); ob[3] = (short)f2bf(o3);
            ob[4] = (short)f2bf(o4); ob[5] = (short)f2bf(o5);
            ob[6] = (short)f2bf(o6); ob[7] = (short)f2bf(o7);
            *(bf16x8*)(hb + ((size_t)node << 7) + co) = ob;
        }
    }
}

// ---------------- launch ----------------

extern "C" void kernel_launch(void* const* d_in, const int* in_sizes, int n_in,
                              void* d_out, int out_size, void* d_ws, size_t ws_size,
                              hipStream_t stream) {
    const float* x          = (const float*)d_in[0];
    const int*   label      = (const int*)d_in[1];
    const int*   edge_index = (const int*)d_in[2];
    const int*   edge_rel   = (const int*)d_in[3];
    const float* label_emb  = (const float*)d_in[4];
    const float* in_proj_w  = (const float*)d_in[5];
    const float* in_proj_b  = (const float*)d_in[6];
    const float* rel_emb    = (const float*)d_in[7];
    const float* lin_neigh_w = (const float*)d_in[8];
    const float* lin_self_w  = (const float*)d_in[9];
    const float* lin_self_b  = (const float*)d_in[10];
    const float* lin_rel_w   = (const float*)d_in[11];
    const float* ln_g        = (const float*)d_in[12];
    const float* ln_b        = (const float*)d_in[13];
    float* h = (float*)d_out;

    char* p = (char*)d_ws;
    auto alloc = [&](size_t bytes) {
        char* r = p;
        p += (bytes + 255) & ~(size_t)255;
        return r;
    };
    int* gbh        = (int*)alloc((size_t)NB * 4);
    int* bucket_off = (int*)alloc((size_t)(NB + 1) * 4);
    int* gcur       = (int*)alloc((size_t)NB * 4);
    int* offsets    = (int*)alloc((size_t)(N_NODES + 1) * 4);
    unsigned* csr_pk = (unsigned*)alloc((size_t)N_EDGES * 4);
    unsigned* staged_pk = (unsigned*)alloc((size_t)N_EDGES * 4);
    unsigned char* staged_dl = (unsigned char*)alloc((size_t)N_EDGES);
    unsigned short* hW    = (unsigned short*)alloc((size_t)N_NODES * 128 * 2);
    unsigned short* hsb   = (unsigned short*)alloc((size_t)N_NODES * 128 * 2);
    unsigned short* relW0 = (unsigned short*)alloc((size_t)REL_BUCKETS * 128 * 2);
    unsigned short* relW1 = (unsigned short*)alloc((size_t)REL_BUCKETS * 128 * 2);
    unsigned short* hb    = (unsigned short*)alloc((size_t)N_NODES * 128 * 2);
    unsigned short* Bt0   = (unsigned short*)alloc((size_t)256 * 128 * 2);
    unsigned short* Bt1   = (unsigned short*)alloc((size_t)256 * 128 * 2);
    unsigned short* Btx   = (unsigned short*)alloc((size_t)128 * 160 * 2);
    unsigned short* leb   = (unsigned short*)alloc((size_t)NUM_LABELS * LABEL_DIM * 2);

    const int* src = edge_index;
    const int* dst = edge_index + N_EDGES;

    // CSR build
    hipMemsetAsync(gbh, 0, (size_t)NB * 4, stream);
    bucket_count_kernel<<<784, 256, 0, stream>>>(dst, gbh);
    bucket_scan_kernel<<<1, 256, 0, stream>>>(gbh, bucket_off, gcur);
    bin_scatter_kernel<<<(N_EDGES + EPB - 1) / EPB, 256, 0, stream>>>(
        src, dst, edge_rel, gcur, staged_pk, staged_dl);
    bin_place2_kernel<<<NB, 512, 0, stream>>>(bucket_off, staged_pk, staged_dl, offsets, csr_pk);

    // all weight/embedding prep in one dispatch
    prep_all_kernel<<<PB_IN + PB_LEMB + 2 * PB_DUAL + 2 * PB_RELW, 256, 0, stream>>>(
        in_proj_w, label_emb, lin_neigh_w, lin_self_w, rel_emb, lin_rel_w,
        Btx, leb, Bt0, Bt1, relW0, relW1);

    const int gemm_grid = (N_NODES + 63) / 64;  // 782

    mfma_in_kernel<<<gemm_grid, 256, 0, stream>>>(x, Btx, leb, label, in_proj_b, hb);

    // layer 0
    mfma_dual2_kernel<<<gemm_grid, 256, 0, stream>>>(hb, Bt0, lin_self_b, hW, hsb);
    agg_ln_kernel<false, true><<<(N_NODES + 3) / 4, 256, 0, stream>>>(
        hW, relW0, hsb, offsets, csr_pk, ln_g, ln_b, h, hb);
    // layer 1
    mfma_dual2_kernel<<<gemm_grid, 256, 0, stream>>>(hb, Bt1, lin_self_b + 128, hW, hsb);
    agg_ln_kernel<true, false><<<(N_NODES + 3) / 4, 256, 0, stream>>>(
        hW, relW1, hsb, offsets, csr_pk, ln_g + 128, ln_b + 128, h, hb);
}

// Round 11
// 283.511 us; speedup vs baseline: 1.0032x; 1.0032x over previous
//
#include <hip/hip_runtime.h>
#include <hip/hip_bf16.h>

#define N_NODES 50000
#define N_EDGES 800000
#define D 128
#define LABEL_DIM 32
#define REL_DIM 32
#define REL_BUCKETS 1024
#define NUM_LABELS 1000
#define LN_EPS 1e-5f

#define NB 196     // dst buckets of 256 nodes
#define EPB 1024   // edges per bin_scatter block (4/thread)
#define GEMM_GRID ((N_NODES + 63) / 64)  // 782

typedef short bf16x8 __attribute__((ext_vector_type(8)));
typedef float f32x4 __attribute__((ext_vector_type(4)));

__device__ inline unsigned short f2bf(float f) {
    __hip_bfloat16 h = __float2bfloat16(f);
    return *reinterpret_cast<unsigned short*>(&h);
}
__device__ inline float bf2f(unsigned short u) {
    return __uint_as_float((unsigned)u << 16);
}
__device__ inline float2 bfpair(unsigned d) {
    return make_float2(__uint_as_float(d << 16), __uint_as_float(d & 0xffff0000u));
}
__device__ inline float2 add2(float2 a, float2 b) {
    return make_float2(a.x + b.x, a.y + b.y);
}

// ================= device bodies =================

// ---- bucket_count: LDS histogram of dst>>8 over a 784-block range ----
__device__ void bucket_count_body(int bid, int t, char* smem, const int* __restrict__ dst,
                                  int* __restrict__ gbh) {
    int* hsh = (int*)smem;
    for (int i = t; i < NB; i += 256) hsh[i] = 0;
    __syncthreads();
    for (int e = bid * 256 + t; e < N_EDGES; e += 784 * 256)
        atomicAdd(&hsh[dst[e] >> 8], 1);
    __syncthreads();
    for (int i = t; i < NB; i += 256)
        if (hsh[i]) atomicAdd(&gbh[i], hsh[i]);
}

// ---- bucket_scan: 1 block, exclusive scan of 196 counts ----
__device__ void bucket_scan_body(int t, char* smem, const int* __restrict__ gbh,
                                 int* __restrict__ bucket_off, int* __restrict__ gcur) {
    int* buf = (int*)smem;
    int v = (t < NB) ? gbh[t] : 0;
    buf[t] = v;
    __syncthreads();
    for (int off = 1; off < 256; off <<= 1) {
        int tv = (t >= off) ? buf[t - off] : 0;
        __syncthreads();
        buf[t] += tv;
        __syncthreads();
    }
    int excl = buf[t] - v;
    if (t < NB) {
        bucket_off[t] = excl;
        gcur[t] = excl;
    }
    if (t == NB - 1) bucket_off[NB] = excl + v;
}

// ---- bin_place2 (256-thread): per-bucket node scan + placement ----
__device__ void bin_place2_body(int b, int t, char* smem, const int* __restrict__ bucket_off,
                                const unsigned* __restrict__ staged_pk,
                                const unsigned char* __restrict__ staged_dl,
                                int* __restrict__ offsets, unsigned* __restrict__ csr_pk) {
    int* hist = (int*)smem;
    int* buf = hist + 256;
    int* cur = buf + 256;
    const int beg = bucket_off[b], end = bucket_off[b + 1];
    hist[t] = 0;
    __syncthreads();
    for (int i = beg + t; i < end; i += 256) atomicAdd(&hist[staged_dl[i]], 1);
    __syncthreads();
    int v = hist[t];
    buf[t] = v;
    __syncthreads();
    for (int off = 1; off < 256; off <<= 1) {
        int tv = (t >= off) ? buf[t - off] : 0;
        __syncthreads();
        buf[t] += tv;
        __syncthreads();
    }
    int node_off = beg + buf[t] - v;
    int node = b * 256 + t;
    if (node < N_NODES) offsets[node] = node_off;
    if (b == NB - 1 && t == 0) offsets[N_NODES] = end;
    cur[t] = node_off;
    __syncthreads();
    for (int i = beg + t; i < end; i += 256) {
        int pos = atomicAdd(&cur[staged_dl[i]], 1);
        csr_pk[pos] = staged_pk[i];
    }
}

// ---- prep_all block-range body ----
#define PB_IN 80      // 128*160/256
#define PB_LEMB 125   // 32000/256
#define PB_DUAL 128   // 256*128/256
#define PB_RELW 512   // 1024*128/256
#define PB_ALL (PB_IN + PB_LEMB + 2 * PB_DUAL + 2 * PB_RELW)  // 1485

__device__ void prep_all_body(int bb, int t, char* smem,
                              const float* __restrict__ in_proj_w,
                              const float* __restrict__ label_emb,
                              const float* __restrict__ lin_neigh_w,
                              const float* __restrict__ lin_self_w,
                              const float* __restrict__ rel_emb,
                              const float* __restrict__ lin_rel_w,
                              unsigned short* __restrict__ Btx, unsigned short* __restrict__ leb,
                              unsigned short* __restrict__ Bt0, unsigned short* __restrict__ Bt1,
                              unsigned short* __restrict__ relW0,
                              unsigned short* __restrict__ relW1) {
    if (bb < PB_IN) {
        int idx = bb * 256 + t;
        int n = idx / 160, k = idx % 160;
        Btx[idx] = f2bf(in_proj_w[k * 128 + n]);
        return;
    }
    bb -= PB_IN;
    if (bb < PB_LEMB) {
        int i = bb * 256 + t;
        if (i < NUM_LABELS * LABEL_DIM) leb[i] = f2bf(label_emb[i]);
        return;
    }
    bb -= PB_LEMB;
    if (bb < 2 * PB_DUAL) {
        int l = bb >= PB_DUAL;
        if (l) bb -= PB_DUAL;
        int idx = bb * 256 + t;
        int n = idx >> 7, k = idx & 127;
        const float* Wn = lin_neigh_w + (size_t)l * 128 * 128;
        const float* Ws = lin_self_w + (size_t)l * 128 * 128;
        float v = (n < 128) ? Wn[k * 128 + n] : Ws[k * 128 + (n - 128)];
        (l ? Bt1 : Bt0)[idx] = f2bf(v);
        return;
    }
    bb -= 2 * PB_DUAL;
    {
        int l = bb >= PB_RELW;
        if (l) bb -= PB_RELW;
        const float* re_base = rel_emb + (size_t)l * REL_BUCKETS * REL_DIM;
        const float* Wr = lin_rel_w + (size_t)l * REL_DIM * 128;
        unsigned short* out = l ? relW1 : relW0;
        float* sw = (float*)smem;  // 16 KiB
        for (int i = t; i < REL_DIM * 128; i += 256) sw[i] = Wr[i];
        __syncthreads();
        int idx = bb * 256 + t;
        int r = idx >> 7, c = idx & 127;
        const float* re = re_base + (size_t)r * REL_DIM;
        float a = 0.f;
#pragma unroll
        for (int k = 0; k < REL_DIM; k++) a = fmaf(re[k], sw[k * 128 + c], a);
        out[idx] = f2bf(a);
    }
}

// ---- mfma_half body: one 128-col half GEMM, 32 KiB B-tile ----
__device__ void mfma_half_body(int bx, int half, int t, char* smem,
                               const unsigned short* __restrict__ A,
                               const unsigned short* __restrict__ Bt,
                               const float* __restrict__ bias,
                               unsigned short* __restrict__ outHW,
                               unsigned short* __restrict__ outHS) {
    unsigned short* sB = (unsigned short*)smem;  // 32 KiB
    const unsigned short* Bsrc = Bt + (size_t)half * 128 * 128;
#pragma unroll
    for (int i = 0; i < 8; ++i) {
        int c = t + i * 256;
        int col = c >> 4, kch = c & 15;
        int dstc = col * 16 + (kch ^ (col & 7));
        *(bf16x8*)&sB[dstc * 8] = *(const bf16x8*)&Bsrc[c * 8];
    }
    __syncthreads();

    const int wave = t >> 6, lane = t & 63;
    const int m16 = lane & 15, q = lane >> 4;
    const int r0 = bx * 64 + wave * 16;
    const int arow = r0 + m16;
    const bool avalid = arow < N_NODES;
    const unsigned short* ap = A + (size_t)(avalid ? arow : 0) * 128 + q * 8;

    f32x4 acc[8];
#pragma unroll
    for (int ct = 0; ct < 8; ++ct) acc[ct] = (f32x4){0.f, 0.f, 0.f, 0.f};

#pragma unroll
    for (int ki = 0; ki < 4; ++ki) {
        bf16x8 af = *(const bf16x8*)(ap + ki * 32);
        if (!avalid) af = (bf16x8){0, 0, 0, 0, 0, 0, 0, 0};
        int kch = ki * 4 + q;
#pragma unroll
        for (int ct = 0; ct < 8; ++ct) {
            int col = ct * 16 + m16;
            int chunk = col * 16 + (kch ^ (m16 & 7));
            bf16x8 bf = *(const bf16x8*)&sB[chunk * 8];
            acc[ct] = __builtin_amdgcn_mfma_f32_16x16x32_bf16(af, bf, acc[ct], 0, 0, 0);
        }
    }

    if (half == 0) {
#pragma unroll
        for (int ct = 0; ct < 8; ++ct) {
            int colg = ct * 16 + m16;
#pragma unroll
            for (int r = 0; r < 4; ++r) {
                int row = r0 + q * 4 + r;
                if (row < N_NODES) outHW[(size_t)row * 128 + colg] = f2bf(acc[ct][r]);
            }
        }
    } else {
#pragma unroll
        for (int ct = 0; ct < 8; ++ct) {
            int colg = ct * 16 + m16;
            float bs = bias[colg];
#pragma unroll
            for (int r = 0; r < 4; ++r) {
                int row = r0 + q * 4 + r;
                if (row < N_NODES) outHS[(size_t)row * 128 + colg] = f2bf(acc[ct][r] + bs);
            }
        }
    }
}

// ---- mfma_in body: input proj (fp32 A, K=160, fused lemb+bias+relu) ----
__device__ void mfma_in_body(int bx, int t, char* smem, const float* __restrict__ X,
                             const unsigned short* __restrict__ Btx,
                             const unsigned short* __restrict__ leb,
                             const int* __restrict__ label, const float* __restrict__ bias,
                             unsigned short* __restrict__ outBF) {
    unsigned short* sB = (unsigned short*)smem;  // 40 KiB
#pragma unroll
    for (int i = 0; i < 10; ++i) {
        int c = t + i * 256;
        int col = c / 20, kch = c % 20;
        int dstc = col * 20 + (kch < 16 ? (kch ^ (col & 7)) : kch);
        *(bf16x8*)&sB[dstc * 8] = *(const bf16x8*)&Btx[c * 8];
    }
    __syncthreads();

    const int wave = t >> 6, lane = t & 63;
    const int m16 = lane & 15, q = lane >> 4;
    const int r0 = bx * 64 + wave * 16;
    const int arow = r0 + m16;
    const bool avalid = arow < N_NODES;
    const float* xp = X + (size_t)(avalid ? arow : 0) * 128 + q * 8;

    f32x4 acc[8];
#pragma unroll
    for (int ct = 0; ct < 8; ++ct) acc[ct] = (f32x4){0.f, 0.f, 0.f, 0.f};

#pragma unroll
    for (int ki = 0; ki < 4; ++ki) {
        bf16x8 af;
        if (avalid) {
            float4 v0 = *(const float4*)(xp + ki * 32);
            float4 v1 = *(const float4*)(xp + ki * 32 + 4);
            af[0] = (short)f2bf(v0.x); af[1] = (short)f2bf(v0.y);
            af[2] = (short)f2bf(v0.z); af[3] = (short)f2bf(v0.w);
            af[4] = (short)f2bf(v1.x); af[5] = (short)f2bf(v1.y);
            af[6] = (short)f2bf(v1.z); af[7] = (short)f2bf(v1.w);
        } else {
            af = (bf16x8){0, 0, 0, 0, 0, 0, 0, 0};
        }
        int kch = ki * 4 + q;
#pragma unroll
        for (int ct = 0; ct < 8; ++ct) {
            int col = ct * 16 + m16;
            int chunk = col * 20 + (kch ^ (m16 & 7));
            bf16x8 bf = *(const bf16x8*)&sB[chunk * 8];
            acc[ct] = __builtin_amdgcn_mfma_f32_16x16x32_bf16(af, bf, acc[ct], 0, 0, 0);
        }
    }
    {
        int lb = avalid ? label[arow] : 0;
        bf16x8 af = *(const bf16x8*)(leb + (size_t)lb * LABEL_DIM + q * 8);
        if (!avalid) af = (bf16x8){0, 0, 0, 0, 0, 0, 0, 0};
        int kch = 16 + q;
#pragma unroll
        for (int ct = 0; ct < 8; ++ct) {
            int col = ct * 16 + m16;
            int chunk = col * 20 + kch;
            bf16x8 bf = *(const bf16x8*)&sB[chunk * 8];
            acc[ct] = __builtin_amdgcn_mfma_f32_16x16x32_bf16(af, bf, acc[ct], 0, 0, 0);
        }
    }

#pragma unroll
    for (int ct = 0; ct < 8; ++ct) {
        int colg = ct * 16 + m16;
        float bs = bias[colg];
#pragma unroll
        for (int r = 0; r < 4; ++r) {
            int row = r0 + q * 4 + r;
            if (row < N_NODES) {
                float v = fmaxf(acc[ct][r] + bs, 0.f);
                outBF[(size_t)row * 128 + colg] = f2bf(v);
            }
        }
    }
}

// ================= kernels =================

// K1: prep_all (1485 blocks) U bucket_count (784 blocks)
__global__ __launch_bounds__(256) void prep_count_kernel(
    const float* __restrict__ in_proj_w, const float* __restrict__ label_emb,
    const float* __restrict__ lin_neigh_w, const float* __restrict__ lin_self_w,
    const float* __restrict__ rel_emb, const float* __restrict__ lin_rel_w,
    unsigned short* __restrict__ Btx, unsigned short* __restrict__ leb,
    unsigned short* __restrict__ Bt0, unsigned short* __restrict__ Bt1,
    unsigned short* __restrict__ relW0, unsigned short* __restrict__ relW1,
    const int* __restrict__ dst, int* __restrict__ gbh) {
    __shared__ __align__(16) char smem[REL_DIM * 128 * 4];  // 16 KiB
    const int t = threadIdx.x;
    int bb = blockIdx.x;
    if (bb < PB_ALL) {
        prep_all_body(bb, t, smem, in_proj_w, label_emb, lin_neigh_w, lin_self_w, rel_emb,
                      lin_rel_w, Btx, leb, Bt0, Bt1, relW0, relW1);
    } else {
        bucket_count_body(bb - PB_ALL, t, smem, dst, gbh);
    }
}

// K2: bucket_scan (1 block) U mfma_in (782 blocks)
__global__ __launch_bounds__(256) void scan_in_kernel(
    const int* __restrict__ gbh, int* __restrict__ bucket_off, int* __restrict__ gcur,
    const float* __restrict__ X, const unsigned short* __restrict__ Btx,
    const unsigned short* __restrict__ leb, const int* __restrict__ label,
    const float* __restrict__ bias, unsigned short* __restrict__ outBF) {
    __shared__ __align__(16) char smem[128 * 160 * 2];  // 40 KiB
    const int t = threadIdx.x;
    if (blockIdx.x == 0) {
        bucket_scan_body(t, smem, gbh, bucket_off, gcur);
    } else {
        mfma_in_body(blockIdx.x - 1, t, smem, X, Btx, leb, label, bias, outBF);
    }
}

// K3: bin_scatter (standalone)
__global__ __launch_bounds__(256) void bin_scatter_kernel(const int* __restrict__ src,
                                                          const int* __restrict__ dst,
                                                          const int* __restrict__ rel,
                                                          int* __restrict__ gcur,
                                                          unsigned* __restrict__ staged_pk,
                                                          unsigned char* __restrict__ staged_dl) {
    __shared__ int hist[NB];
    __shared__ int lcur[NB];
    const int t = threadIdx.x;
    for (int i = t; i < NB; i += 256) hist[i] = 0;
    __syncthreads();
    const int e0 = blockIdx.x * EPB;
    unsigned char bb[4], dl[4];
#pragma unroll
    for (int i = 0; i < 4; ++i) {
        int e = e0 + i * 256 + t;
        if (e < N_EDGES) {
            int d = dst[e];
            bb[i] = (unsigned char)(d >> 8);
            dl[i] = (unsigned char)(d & 255);
            atomicAdd(&hist[d >> 8], 1);
        }
    }
    __syncthreads();
    for (int b = t; b < NB; b += 256) {
        int hc = hist[b];
        lcur[b] = hc ? atomicAdd(&gcur[b], hc) : 0;
    }
    __syncthreads();
#pragma unroll
    for (int i = 0; i < 4; ++i) {
        int e = e0 + i * 256 + t;
        if (e < N_EDGES) {
            int pos = atomicAdd(&lcur[bb[i]], 1);
            staged_pk[pos] = (unsigned)src[e] | ((unsigned)rel[e] << 16);
            staged_dl[pos] = dl[i];
        }
    }
}

// K4: bin_place2 (196 blocks) U mfma_half layer (1564 blocks)
__global__ __launch_bounds__(256) void place_gemm_kernel(
    const int* __restrict__ bucket_off, const unsigned* __restrict__ staged_pk,
    const unsigned char* __restrict__ staged_dl, int* __restrict__ offsets,
    unsigned* __restrict__ csr_pk, const unsigned short* __restrict__ A,
    const unsigned short* __restrict__ Bt, const float* __restrict__ bias,
    unsigned short* __restrict__ outHW, unsigned short* __restrict__ outHS) {
    __shared__ __align__(16) char smem[128 * 128 * 2];  // 32 KiB
    const int t = threadIdx.x;
    int bb = blockIdx.x;
    if (bb < NB) {
        bin_place2_body(bb, t, smem, bucket_off, staged_pk, staged_dl, offsets, csr_pk);
    } else {
        bb -= NB;
        int half = bb >= GEMM_GRID;
        mfma_half_body(half ? bb - GEMM_GRID : bb, half, t, smem, A, Bt, bias, outHW, outHS);
    }
}

// K6: plain mfma_half (dim3(782,2)) for layer 1
__global__ __launch_bounds__(256) void mfma_half_kernel(const unsigned short* __restrict__ A,
                                                        const unsigned short* __restrict__ Bt,
                                                        const float* __restrict__ bias,
                                                        unsigned short* __restrict__ outHW,
                                                        unsigned short* __restrict__ outHS) {
    __shared__ __align__(16) char smem[128 * 128 * 2];
    mfma_half_body(blockIdx.x, blockIdx.y, threadIdx.x, smem, A, Bt, bias, outHW, outHS);
}

// ---------------- edge gather + mean + self + relu + layernorm ----------------
template <bool WF32, bool WBF16>
__global__ __launch_bounds__(256) void agg_ln_kernel(const unsigned short* __restrict__ hW,
                                                     const unsigned short* __restrict__ relW,
                                                     const unsigned short* __restrict__ hsb,
                                                     const int* __restrict__ offsets,
                                                     const unsigned* __restrict__ csr_pk,
                                                     const float* __restrict__ g,
                                                     const float* __restrict__ b,
                                                     float* __restrict__ h,
                                                     unsigned short* __restrict__ hb) {
    const int wave = threadIdx.x >> 6;
    const int lane = threadIdx.x & 63;
    const int node = blockIdx.x * 4 + wave;
    if (node >= N_NODES) return;
    const int q = lane >> 4, l16 = lane & 15;
    const int beg = offsets[node], end = offsets[node + 1];
    const int co = l16 * 8;

    float2 acc2[4];
#pragma unroll
    for (int j = 0; j < 4; ++j) acc2[j] = make_float2(0.f, 0.f);

    int e = beg;
    for (; e + 8 <= end; e += 8) {
        unsigned pk0 = csr_pk[e + q];
        unsigned pk1 = csr_pk[e + 4 + q];
        uint4 hv0 = *(const uint4*)(hW + ((size_t)(pk0 & 0xffffu) << 7) + co);
        uint4 rv0 = *(const uint4*)(relW + ((size_t)(pk0 >> 16) << 7) + co);
        uint4 hv1 = *(const uint4*)(hW + ((size_t)(pk1 & 0xffffu) << 7) + co);
        uint4 rv1 = *(const uint4*)(relW + ((size_t)(pk1 >> 16) << 7) + co);
        acc2[0] = add2(acc2[0], add2(bfpair(hv0.x), bfpair(rv0.x)));
        acc2[1] = add2(acc2[1], add2(bfpair(hv0.y), bfpair(rv0.y)));
        acc2[2] = add2(acc2[2], add2(bfpair(hv0.z), bfpair(rv0.z)));
        acc2[3] = add2(acc2[3], add2(bfpair(hv0.w), bfpair(rv0.w)));
        acc2[0] = add2(acc2[0], add2(bfpair(hv1.x), bfpair(rv1.x)));
        acc2[1] = add2(acc2[1], add2(bfpair(hv1.y), bfpair(rv1.y)));
        acc2[2] = add2(acc2[2], add2(bfpair(hv1.z), bfpair(rv1.z)));
        acc2[3] = add2(acc2[3], add2(bfpair(hv1.w), bfpair(rv1.w)));
    }
    if (e < end) {  // masked tail (1..7 edges)
        int i0 = e + q, i1 = e + 4 + q;
        float m0 = 1.f, m1 = 1.f;
        if (i0 >= end) { i0 = beg; m0 = 0.f; }
        if (i1 >= end) { i1 = beg; m1 = 0.f; }
        unsigned pk0 = csr_pk[i0];
        unsigned pk1 = csr_pk[i1];
        uint4 hv0 = *(const uint4*)(hW + ((size_t)(pk0 & 0xffffu) << 7) + co);
        uint4 rv0 = *(const uint4*)(relW + ((size_t)(pk0 >> 16) << 7) + co);
        uint4 hv1 = *(const uint4*)(hW + ((size_t)(pk1 & 0xffffu) << 7) + co);
        uint4 rv1 = *(const uint4*)(relW + ((size_t)(pk1 >> 16) << 7) + co);
        unsigned dw0[4] = {hv0.x, hv0.y, hv0.z, hv0.w};
        unsigned dr0[4] = {rv0.x, rv0.y, rv0.z, rv0.w};
        unsigned dw1[4] = {hv1.x, hv1.y, hv1.z, hv1.w};
        unsigned dr1[4] = {rv1.x, rv1.y, rv1.z, rv1.w};
#pragma unroll
        for (int j = 0; j < 4; ++j) {
            float2 v0 = add2(bfpair(dw0[j]), bfpair(dr0[j]));
            acc2[j].x = fmaf(m0, v0.x, acc2[j].x);
            acc2[j].y = fmaf(m0, v0.y, acc2[j].y);
        }
#pragma unroll
        for (int j = 0; j < 4; ++j) {
            float2 v1 = add2(bfpair(dw1[j]), bfpair(dr1[j]));
            acc2[j].x = fmaf(m1, v1.x, acc2[j].x);
            acc2[j].y = fmaf(m1, v1.y, acc2[j].y);
        }
    }

    float acc[8];
#pragma unroll
    for (int j = 0; j < 4; ++j) {
        acc[2 * j] = acc2[j].x;
        acc[2 * j + 1] = acc2[j].y;
    }
#pragma unroll
    for (int j = 0; j < 8; ++j) {
        acc[j] += __shfl_xor(acc[j], 16);
        acc[j] += __shfl_xor(acc[j], 32);
    }

    float inv = (end > beg) ? 1.f / (float)(end - beg) : 0.f;
    bf16x8 hsv = *(const bf16x8*)(hsb + ((size_t)node << 7) + co);
    float v[8];
    float s_sum = 0.f;
#pragma unroll
    for (int j = 0; j < 8; ++j) {
        v[j] = fmaxf(bf2f((unsigned short)hsv[j]) + acc[j] * inv, 0.f);
        s_sum += v[j];
    }
#pragma unroll
    for (int o = 8; o > 0; o >>= 1) s_sum += __shfl_xor(s_sum, o);
    float mu = s_sum * (1.f / 128.f);
    float qs = 0.f;
    float d[8];
#pragma unroll
    for (int j = 0; j < 8; ++j) {
        d[j] = v[j] - mu;
        qs += d[j] * d[j];
    }
#pragma unroll
    for (int o = 8; o > 0; o >>= 1) qs += __shfl_xor(qs, o);
    float rstd = rsqrtf(qs * (1.f / 128.f) + LN_EPS);

    if (q == 0) {
        float4 g0 = *(const float4*)(g + co), g1 = *(const float4*)(g + co + 4);
        float4 b0 = *(const float4*)(b + co), b1 = *(const float4*)(b + co + 4);
        float o0 = d[0] * rstd * g0.x + b0.x;
        float o1 = d[1] * rstd * g0.y + b0.y;
        float o2 = d[2] * rstd * g0.z + b0.z;
        float o3 = d[3] * rstd * g0.w + b0.w;
        float o4 = d[4] * rstd * g1.x + b1.x;
        float o5 = d[5] * rstd * g1.y + b1.y;
        float o6 = d[6] * rstd * g1.z + b1.z;
        float o7 = d[7] * rstd * g1.w + b1.w;
        if (WF32) {
            *(float4*)(h + ((size_t)node << 7) + co) = make_float4(o0, o1, o2, o3);
            *(float4*)(h + ((size_t)node << 7) + co + 4) = make_float4(o4, o5, o6, o7);
        }
        if (WBF16) {
            bf16x8 ob;
            ob[0] = (short)f2bf(o0); ob[1] = (short)f2bf(o1);
            ob[2] = (short)f2bf(o2); ob[3] = (short)f2bf(o3);
            ob[4] = (short)f2bf(o4); ob[5] = (short)f2bf(o5);
            ob[6] = (short)f2bf(o6); ob[7] = (short)f2bf(o7);
            *(bf16x8*)(hb + ((size_t)node << 7) + co) = ob;
        }
    }
}

// ---------------- launch ----------------

extern "C" void kernel_launch(void* const* d_in, const int* in_sizes, int n_in,
                              void* d_out, int out_size, void* d_ws, size_t ws_size,
                              hipStream_t stream) {
    const float* x          = (const float*)d_in[0];
    const int*   label      = (const int*)d_in[1];
    const int*   edge_index = (const int*)d_in[2];
    const int*   edge_rel   = (const int*)d_in[3];
    const float* label_emb  = (const float*)d_in[4];
    const float* in_proj_w  = (const float*)d_in[5];
    const float* in_proj_b  = (const float*)d_in[6];
    const float* rel_emb    = (const float*)d_in[7];
    const float* lin_neigh_w = (const float*)d_in[8];
    const float* lin_self_w  = (const float*)d_in[9];
    const float* lin_self_b  = (const float*)d_in[10];
    const float* lin_rel_w   = (const float*)d_in[11];
    const float* ln_g        = (const float*)d_in[12];
    const float* ln_b        = (const float*)d_in[13];
    float* h = (float*)d_out;

    char* p = (char*)d_ws;
    auto alloc = [&](size_t bytes) {
        char* r = p;
        p += (bytes + 255) & ~(size_t)255;
        return r;
    };
    int* gbh        = (int*)alloc((size_t)NB * 4);
    int* bucket_off = (int*)alloc((size_t)(NB + 1) * 4);
    int* gcur       = (int*)alloc((size_t)NB * 4);
    int* offsets    = (int*)alloc((size_t)(N_NODES + 1) * 4);
    unsigned* csr_pk = (unsigned*)alloc((size_t)N_EDGES * 4);
    unsigned* staged_pk = (unsigned*)alloc((size_t)N_EDGES * 4);
    unsigned char* staged_dl = (unsigned char*)alloc((size_t)N_EDGES);
    unsigned short* hW    = (unsigned short*)alloc((size_t)N_NODES * 128 * 2);
    unsigned short* hsb   = (unsigned short*)alloc((size_t)N_NODES * 128 * 2);
    unsigned short* relW0 = (unsigned short*)alloc((size_t)REL_BUCKETS * 128 * 2);
    unsigned short* relW1 = (unsigned short*)alloc((size_t)REL_BUCKETS * 128 * 2);
    unsigned short* hb    = (unsigned short*)alloc((size_t)N_NODES * 128 * 2);
    unsigned short* Bt0   = (unsigned short*)alloc((size_t)256 * 128 * 2);
    unsigned short* Bt1   = (unsigned short*)alloc((size_t)256 * 128 * 2);
    unsigned short* Btx   = (unsigned short*)alloc((size_t)128 * 160 * 2);
    unsigned short* leb   = (unsigned short*)alloc((size_t)NUM_LABELS * LABEL_DIM * 2);

    const int* src = edge_index;
    const int* dst = edge_index + N_EDGES;

    hipMemsetAsync(gbh, 0, (size_t)NB * 4, stream);

    // K1: all weight prep + bucket histogram
    prep_count_kernel<<<PB_ALL + 784, 256, 0, stream>>>(
        in_proj_w, label_emb, lin_neigh_w, lin_self_w, rel_emb, lin_rel_w,
        Btx, leb, Bt0, Bt1, relW0, relW1, dst, gbh);

    // K2: bucket scan + input-proj GEMM
    scan_in_kernel<<<1 + GEMM_GRID, 256, 0, stream>>>(gbh, bucket_off, gcur, x, Btx, leb, label,
                                                      in_proj_b, hb);

    // K3: bucket scatter
    bin_scatter_kernel<<<(N_EDGES + EPB - 1) / EPB, 256, 0, stream>>>(
        src, dst, edge_rel, gcur, staged_pk, staged_dl);

    // K4: CSR finalize + layer-0 dual GEMM
    place_gemm_kernel<<<NB + 2 * GEMM_GRID, 256, 0, stream>>>(
        bucket_off, staged_pk, staged_dl, offsets, csr_pk, hb, Bt0, lin_self_b, hW, hsb);

    // K5: layer-0 aggregate + LN
    agg_ln_kernel<false, true><<<(N_NODES + 3) / 4, 256, 0, stream>>>(
        hW, relW0, hsb, offsets, csr_pk, ln_g, ln_b, h, hb);

    // K6: layer-1 dual GEMM
    mfma_half_kernel<<<dim3(GEMM_GRID, 2), 256, 0, stream>>>(hb, Bt1, lin_self_b + 128, hW, hsb);

    // K7: layer-1 aggregate + LN
    agg_ln_kernel<true, false><<<(N_NODES + 3) / 4, 256, 0, stream>>>(
        hW, relW1, hsb, offsets, csr_pk, ln_g + 128, ln_b + 128, h, hb);
}